// Round 1
// baseline (129.895 us; speedup 1.0000x reference)
//
#include <hip/hip_runtime.h>

#define N_NEUR 9216   // L*L
#define N_FEAT 1024
#define LR 0.1f

// ---------------------------------------------------------------------------
// Kernel 1: per-row squared distance + global argmin via packed u64 atomicMin.
// Block = 256 threads handles one row (256 * float4 = 1024 elems).
// key = (float_bits(dist2) << 32) | row :  dist2 >= 0 so its IEEE bits are
// monotone as uint; min key -> min dist2, ties -> smallest row (== jnp.argmin).
// ---------------------------------------------------------------------------
__global__ __launch_bounds__(256) void som_dist_argmin(
    const float* __restrict__ x, const float* __restrict__ W,
    unsigned long long* __restrict__ key)
{
    const int row = blockIdx.x;
    const int t   = threadIdx.x;

    const float4 a = reinterpret_cast<const float4*>(x)[t];
    const float4 b = reinterpret_cast<const float4*>(W + (size_t)row * N_FEAT)[t];

    const float dx = a.x - b.x, dy = a.y - b.y, dz = a.z - b.z, dw = a.w - b.w;
    float s = dx * dx + dy * dy + dz * dz + dw * dw;

    // wave64 reduce
    #pragma unroll
    for (int o = 32; o > 0; o >>= 1) s += __shfl_down(s, o);

    __shared__ float partial[4];
    if ((t & 63) == 0) partial[t >> 6] = s;
    __syncthreads();

    if (t == 0) {
        const float tot = partial[0] + partial[1] + partial[2] + partial[3];
        const unsigned long long k =
            ((unsigned long long)__float_as_uint(tot) << 32) | (unsigned)row;
        atomicMin(key, k);
    }
}

// ---------------------------------------------------------------------------
// Kernel 2: W_new = W + LR * h[row] * (x - W),  h = exp(-nhb[bmu][row] / 2)
// Block per row, float4 path. All lanes read the same bmu/nhb scalar (L2
// broadcast, cheap).
// ---------------------------------------------------------------------------
__global__ __launch_bounds__(256) void som_update(
    const float* __restrict__ x, const float* __restrict__ W,
    const float* __restrict__ nhb,
    const unsigned long long* __restrict__ key,
    float* __restrict__ out)
{
    const int row = blockIdx.x;
    const int t   = threadIdx.x;

    const unsigned bmu = (unsigned)(*key & 0xFFFFFFFFull);
    const float h  = expf(-0.5f * nhb[(size_t)bmu * N_NEUR + row]);
    const float lh = LR * h;

    const float4 a = reinterpret_cast<const float4*>(x)[t];
    const float4 b = reinterpret_cast<const float4*>(W + (size_t)row * N_FEAT)[t];

    float4 r;
    r.x = b.x + lh * (a.x - b.x);
    r.y = b.y + lh * (a.y - b.y);
    r.z = b.z + lh * (a.z - b.z);
    r.w = b.w + lh * (a.w - b.w);

    reinterpret_cast<float4*>(out + (size_t)row * N_FEAT)[t] = r;
}

extern "C" void kernel_launch(void* const* d_in, const int* in_sizes, int n_in,
                              void* d_out, int out_size, void* d_ws, size_t ws_size,
                              hipStream_t stream)
{
    const float* x   = (const float*)d_in[0];
    const float* W   = (const float*)d_in[1];
    const float* nhb = (const float*)d_in[2];
    float* out       = (float*)d_out;
    unsigned long long* key = (unsigned long long*)d_ws;

    // init argmin key to +inf-like max (graph-capture-safe async memset)
    hipMemsetAsync(key, 0xFF, sizeof(unsigned long long), stream);

    som_dist_argmin<<<N_NEUR, 256, 0, stream>>>(x, W, key);
    som_update<<<N_NEUR, 256, 0, stream>>>(x, W, nhb, key, out);
}

// Round 2
// 28.697 us; speedup vs baseline: 4.5265x; 4.5265x over previous
//
#include <hip/hip_runtime.h>

#define N_NEUR 9216   // L*L
#define N_FEAT 1024
#define LR 0.1f

// ---------------------------------------------------------------------------
// Kernel 1: per-row squared distance -> packed key ws[row].
// key = (float_bits(dist2) << 32) | row : dist2 >= 0 so IEEE bits are monotone
// as uint; min key -> min dist2, ties -> smallest row (== jnp.argmin over the
// monotone sqrt). NO atomics — plain coalesced store per row.
// ---------------------------------------------------------------------------
__global__ __launch_bounds__(256) void som_dist(
    const float* __restrict__ x, const float* __restrict__ W,
    unsigned long long* __restrict__ keys)
{
    const int row = blockIdx.x;
    const int t   = threadIdx.x;

    const float4 a = reinterpret_cast<const float4*>(x)[t];
    const float4 b = reinterpret_cast<const float4*>(W + (size_t)row * N_FEAT)[t];

    const float dx = a.x - b.x, dy = a.y - b.y, dz = a.z - b.z, dw = a.w - b.w;
    float s = dx * dx + dy * dy + dz * dz + dw * dw;

    #pragma unroll
    for (int o = 32; o > 0; o >>= 1) s += __shfl_down(s, o);

    __shared__ float partial[4];
    if ((t & 63) == 0) partial[t >> 6] = s;
    __syncthreads();

    if (t == 0) {
        const float tot = partial[0] + partial[1] + partial[2] + partial[3];
        keys[row] = ((unsigned long long)__float_as_uint(tot) << 32) | (unsigned)row;
    }
}

// ---------------------------------------------------------------------------
// Kernel 2: single-block min-reduce of 9216 keys -> bmu index. 1024 threads,
// 9 strided loads each, wave64 shuffle reduce + LDS across 16 waves.
// ---------------------------------------------------------------------------
__global__ __launch_bounds__(1024) void som_argmin(
    const unsigned long long* __restrict__ keys,
    unsigned* __restrict__ bmu_out)
{
    const int t = threadIdx.x;
    unsigned long long m = ~0ull;

    for (int i = t; i < N_NEUR; i += 1024) {
        const unsigned long long k = keys[i];
        m = k < m ? k : m;
    }

    #pragma unroll
    for (int o = 32; o > 0; o >>= 1) {
        const unsigned long long k = __shfl_down(m, o);
        m = k < m ? k : m;
    }

    __shared__ unsigned long long wmin[16];
    if ((t & 63) == 0) wmin[t >> 6] = m;
    __syncthreads();

    if (t == 0) {
        #pragma unroll
        for (int w = 1; w < 16; ++w) m = wmin[w] < m ? wmin[w] : m;
        *bmu_out = (unsigned)(m & 0xFFFFFFFFu);
    }
}

// ---------------------------------------------------------------------------
// Kernel 3: W_new = W + LR * h[row] * (x - W),  h = exp(-nhb[bmu][row] / 2)
// ---------------------------------------------------------------------------
__global__ __launch_bounds__(256) void som_update(
    const float* __restrict__ x, const float* __restrict__ W,
    const float* __restrict__ nhb,
    const unsigned* __restrict__ bmu_ptr,
    float* __restrict__ out)
{
    const int row = blockIdx.x;
    const int t   = threadIdx.x;

    const unsigned bmu = *bmu_ptr;
    const float h  = expf(-0.5f * nhb[(size_t)bmu * N_NEUR + row]);
    const float lh = LR * h;

    const float4 a = reinterpret_cast<const float4*>(x)[t];
    const float4 b = reinterpret_cast<const float4*>(W + (size_t)row * N_FEAT)[t];

    float4 r;
    r.x = b.x + lh * (a.x - b.x);
    r.y = b.y + lh * (a.y - b.y);
    r.z = b.z + lh * (a.z - b.z);
    r.w = b.w + lh * (a.w - b.w);

    reinterpret_cast<float4*>(out + (size_t)row * N_FEAT)[t] = r;
}

extern "C" void kernel_launch(void* const* d_in, const int* in_sizes, int n_in,
                              void* d_out, int out_size, void* d_ws, size_t ws_size,
                              hipStream_t stream)
{
    const float* x   = (const float*)d_in[0];
    const float* W   = (const float*)d_in[1];
    const float* nhb = (const float*)d_in[2];
    float* out       = (float*)d_out;

    unsigned long long* keys = (unsigned long long*)d_ws;
    unsigned* bmu            = (unsigned*)(keys + N_NEUR);

    som_dist<<<N_NEUR, 256, 0, stream>>>(x, W, keys);
    som_argmin<<<1, 1024, 0, stream>>>(keys, bmu);
    som_update<<<N_NEUR, 256, 0, stream>>>(x, W, nhb, bmu, out);
}